// Round 1
// baseline (427.157 us; speedup 1.0000x reference)
//
#include <hip/hip_runtime.h>
#include <math.h>

#define N 4096
#define NH 2048         // N/2
#define THREADS 256
#define BATCH 8192

// ---------------------------------------------------------------------------
// prep: build full Hermitian spectrum H[0..N) and twiddle table tw[0..N/2)
//   H[n] = w_real[n] + i*w_imag[n]          for n <= N/2  (imag forced 0 at Nyquist)
//   H[n] = conj(H[N-n])                     for n >  N/2
//   tw[j] = exp(-2*pi*i*j/N)
// ---------------------------------------------------------------------------
__global__ void prep_kernel(const float* __restrict__ wr, const float* __restrict__ wi,
                            float2* __restrict__ H, float2* __restrict__ tw) {
    int i = blockIdx.x * blockDim.x + threadIdx.x;
    if (i < NH) {
        double ang = -2.0 * M_PI * (double)i / (double)N;
        tw[i] = make_float2((float)cos(ang), (float)sin(ang));
    }
    if (i < N) {
        float re, im;
        if (i <= N / 2) {
            re = wr[i];
            im = (i == N / 2) ? 0.0f : wi[i];   // reference takes .real at Nyquist
        } else {
            re = wr[N - i];
            im = -wi[N - i];
        }
        H[i] = make_float2(re, im);
    }
}

// ---------------------------------------------------------------------------
// fft_conv: one block = 2 rows packed as one complex FFT (z = x1 + i*x2).
// Stockham radix-2 (autosort, ping-pong), 12 fwd stages, pointwise *H,
// 12 inverse stages (conjugate twiddles), scale 1/N, add bias.
// Since T(x)=ifft(H*fft(x)) is C-linear and real->real (H Hermitian):
//   T(x1 + i*x2) = y1 + i*y2.
// ---------------------------------------------------------------------------
__global__ __launch_bounds__(THREADS) void fft_conv_kernel(
        const float* __restrict__ x, const float2* __restrict__ H,
        const float2* __restrict__ tw, const float* __restrict__ bias,
        float* __restrict__ out) {
    __shared__ float2 bufA[N];
    __shared__ float2 bufB[N];
    const int t = threadIdx.x;
    const long base1 = (long)(2 * blockIdx.x) * N;
    const long base2 = base1 + N;

    // load two rows as one complex sequence
    for (int i = t; i < N; i += THREADS)
        bufA[i] = make_float2(x[base1 + i], x[base2 + i]);
    __syncthreads();

    float2* a = bufA;
    float2* b = bufB;

    // ---- forward FFT: 12 Stockham radix-2 stages ----
    // invariant: l*m = NH; butterfly q=(j,k): j=q>>s, k=q&(m-1), jm=q-k
    // reads  a[q], a[q+NH]
    // writes b[k+2jm] = c0+c1 ; b[k+2jm+m] = tw[jm]*(c0-c1)
    for (int s = 0; s < 12; ++s) {
        const int m = 1 << s;
        #pragma unroll
        for (int q = t; q < NH; q += THREADS) {
            const int k  = q & (m - 1);
            const int jm = q - k;            // j*m == twiddle index j<<s
            float2 c0 = a[q];
            float2 c1 = a[q + NH];
            float2 w  = tw[jm];
            float2 su = make_float2(c0.x + c1.x, c0.y + c1.y);
            float2 di = make_float2(c0.x - c1.x, c0.y - c1.y);
            float2 wd = make_float2(w.x * di.x - w.y * di.y,
                                    w.x * di.y + w.y * di.x);
            b[k + 2 * jm]     = su;
            b[k + 2 * jm + m] = wd;
        }
        __syncthreads();
        float2* tp = a; a = b; b = tp;
    }
    // after 12 swaps, a == bufA and holds FFT(z)

    // ---- pointwise multiply by spectrum ----
    for (int i = t; i < N; i += THREADS) {
        float2 Z = a[i];
        float2 h = H[i];
        a[i] = make_float2(Z.x * h.x - Z.y * h.y,
                           Z.x * h.y + Z.y * h.x);
    }
    __syncthreads();

    // ---- inverse FFT: same stages, conjugate twiddles ----
    for (int s = 0; s < 12; ++s) {
        const int m = 1 << s;
        #pragma unroll
        for (int q = t; q < NH; q += THREADS) {
            const int k  = q & (m - 1);
            const int jm = q - k;
            float2 c0 = a[q];
            float2 c1 = a[q + NH];
            float2 w  = tw[jm];
            w.y = -w.y;                      // conj -> inverse transform
            float2 su = make_float2(c0.x + c1.x, c0.y + c1.y);
            float2 di = make_float2(c0.x - c1.x, c0.y - c1.y);
            float2 wd = make_float2(w.x * di.x - w.y * di.y,
                                    w.x * di.y + w.y * di.x);
            b[k + 2 * jm]     = su;
            b[k + 2 * jm + m] = wd;
        }
        __syncthreads();
        float2* tp = a; a = b; b = tp;
    }
    // a == bufA holds N * ifft(H*FFT(z)); real->row1, imag->row2

    const float inv = 1.0f / (float)N;
    for (int i = t; i < N; i += THREADS) {
        float2 v = a[i];
        float bb = bias[i];
        out[base1 + i] = fmaf(v.x, inv, bb);
        out[base2 + i] = fmaf(v.y, inv, bb);
    }
}

// ---------------------------------------------------------------------------
extern "C" void kernel_launch(void* const* d_in, const int* in_sizes, int n_in,
                              void* d_out, int out_size, void* d_ws, size_t ws_size,
                              hipStream_t stream) {
    const float* x  = (const float*)d_in[0];   // (8192, 4096)
    const float* wr = (const float*)d_in[1];   // (2049,)
    const float* wi = (const float*)d_in[2];   // (2049,)
    const float* bs = (const float*)d_in[3];   // (4096,)
    float* out = (float*)d_out;                // (8192, 4096)

    float2* H  = (float2*)d_ws;                                   // 32 KB
    float2* tw = (float2*)((char*)d_ws + (size_t)N * sizeof(float2)); // 16 KB

    prep_kernel<<<dim3((N + THREADS - 1) / THREADS), dim3(THREADS), 0, stream>>>(wr, wi, H, tw);
    fft_conv_kernel<<<dim3(BATCH / 2), dim3(THREADS), 0, stream>>>(x, H, tw, bs, out);
}

// Round 2
// 313.739 us; speedup vs baseline: 1.3615x; 1.3615x over previous
//
#include <hip/hip_runtime.h>
#include <math.h>

#define N 4096
#define THREADS 256
#define BATCH 8192

// XOR swizzle: bijection on [0,4096) making all three LDS access families
// (stride-256 reads, 16-contiguous writes, stride-16 writes) bank-minimal.
#define SWZ(i) ((i) ^ (((i) >> 4) & 15))
// dft16 stores X_p at slot IDX16(p) (base-4 digit swap; involution)
#define IDX16(p) ((((p) & 3) << 2) | ((p) >> 2))

__device__ __forceinline__ float2 cmul(float2 a, float2 b) {
    return make_float2(fmaf(a.x, b.x, -(a.y * b.y)), fmaf(a.x, b.y, a.y * b.x));
}

// radix-4 butterfly at v[base + r*stride]; forward uses w4 = -i, inverse +i
template<bool INV>
__device__ __forceinline__ void dft4(float2* v, int base, int stride) {
    float2 a = v[base], b = v[base + stride], c = v[base + 2 * stride], d = v[base + 3 * stride];
    float2 t0 = make_float2(a.x + c.x, a.y + c.y);
    float2 t1 = make_float2(a.x - c.x, a.y - c.y);
    float2 t2 = make_float2(b.x + d.x, b.y + d.y);
    float2 t3 = make_float2(b.x - d.x, b.y - d.y);
    float2 j3 = INV ? make_float2(-t3.y, t3.x) : make_float2(t3.y, -t3.x);
    v[base]              = make_float2(t0.x + t2.x, t0.y + t2.y);
    v[base + stride]     = make_float2(t1.x + j3.x, t1.y + j3.y);
    v[base + 2 * stride] = make_float2(t0.x - t2.x, t0.y - t2.y);
    v[base + 3 * stride] = make_float2(t1.x - j3.x, t1.y - j3.y);
}

// internal W16^{n1*k2} twiddles; slot set is symmetric under n1<->k2 so this
// works for both dft16 and dft16_perm.
template<bool INV>
__device__ __forceinline__ void tw16(float2* v) {
    const float C1 = 0.9238795325112867f;
    const float S1 = 0.3826834323650898f;
    const float R2 = 0.7071067811865476f;
    const float s = INV ? 1.0f : -1.0f;
    const float2 W1 = make_float2(C1, s * S1);
    const float2 W2 = make_float2(R2, s * R2);
    const float2 W3 = make_float2(S1, s * C1);
    const float2 W6 = make_float2(-R2, s * R2);
    const float2 W9 = make_float2(-C1, -s * S1);
    v[5]  = cmul(v[5],  W1);
    v[9]  = cmul(v[9],  W2);
    v[13] = cmul(v[13], W3);
    v[6]  = cmul(v[6],  W2);
    { float2 z = v[10]; v[10] = INV ? make_float2(-z.y, z.x) : make_float2(z.y, -z.x); }  // W4 = -/+ i
    v[14] = cmul(v[14], W6);
    v[7]  = cmul(v[7],  W3);
    v[11] = cmul(v[11], W6);
    v[15] = cmul(v[15], W9);
}

// input sample n at v[n]; output X_p at v[IDX16(p)]
template<bool INV>
__device__ __forceinline__ void dft16(float2* v) {
    #pragma unroll
    for (int n1 = 0; n1 < 4; ++n1) dft4<INV>(v, n1, 4);
    tw16<INV>(v);
    #pragma unroll
    for (int k2 = 0; k2 < 4; ++k2) dft4<INV>(v, 4 * k2, 1);
}

// input sample n at v[IDX16(n)]; output X_p at v[p]
template<bool INV>
__device__ __forceinline__ void dft16_perm(float2* v) {
    #pragma unroll
    for (int n1 = 0; n1 < 4; ++n1) dft4<INV>(v, 4 * n1, 1);
    tw16<INV>(v);
    #pragma unroll
    for (int k2 = 0; k2 < 4; ++k2) dft4<INV>(v, k2, 4);
}

// ---------------------------------------------------------------------------
// prep: full Hermitian spectrum H[0..N) and FULL twiddle table tw[0..N)
// ---------------------------------------------------------------------------
__global__ void prep_kernel(const float* __restrict__ wr, const float* __restrict__ wi,
                            float2* __restrict__ H, float2* __restrict__ tw) {
    int i = blockIdx.x * blockDim.x + threadIdx.x;
    if (i < N) {
        double ang = -2.0 * M_PI * (double)i / (double)N;
        tw[i] = make_float2((float)cos(ang), (float)sin(ang));
        float re, im;
        if (i <= N / 2) {
            re = wr[i];
            im = (i == N / 2) ? 0.0f : wi[i];
        } else {
            re = wr[N - i];
            im = -wi[N - i];
        }
        H[i] = make_float2(re, im);
    }
}

// ---------------------------------------------------------------------------
// One block = 2 rows packed as one complex sequence (z = x1 + i*x2; T is
// C-linear and real->real since H is Hermitian, so T(z) = y1 + i*y2).
// Radix-16 Stockham: stage (m): q=t, k=q%m, j=q/m;
//   d_p = sum_r a[q + r*256] w16^{rp};  b[k+(16j+p)m] = w_N^{jmp} d_p
// Stages m=1,16,256 forward; H-multiply fully in registers; m=1,16,256
// inverse (conjugated); single in-place swizzled LDS buffer.
// ---------------------------------------------------------------------------
__global__ __launch_bounds__(THREADS, 4) void fft_conv_kernel(
        const float* __restrict__ x, const float2* __restrict__ H,
        const float2* __restrict__ tw, const float* __restrict__ bias,
        float* __restrict__ out) {
    __shared__ float2 lds[N];   // 32 KB -> 4+ blocks/CU
    const int t = threadIdx.x;
    const long base1 = (long)(2 * blockIdx.x) * N;
    const long base2 = base1 + N;

    float2 v[16];

    // ---- load: fwd stage A reads pattern t+256r straight from global ----
    #pragma unroll
    for (int r = 0; r < 16; ++r) {
        v[r].x = x[base1 + t + 256 * r];
        v[r].y = x[base2 + t + 256 * r];
    }

    // ---- fwd A (m=1, k=0, j=t): twiddle w^(t*p), write 16t+p ----
    dft16<false>(v);
    #pragma unroll
    for (int p = 1; p < 16; ++p)
        v[IDX16(p)] = cmul(v[IDX16(p)], tw[t * p]);        // t*p <= 3825 < 4096
    #pragma unroll
    for (int p = 0; p < 16; ++p)
        lds[SWZ(16 * t + p)] = v[IDX16(p)];
    __syncthreads();

    // ---- fwd B (m=16): read t+256r, twiddle w^(16jp), write k+256j+16p ----
    #pragma unroll
    for (int r = 0; r < 16; ++r) v[r] = lds[SWZ(t + 256 * r)];
    __syncthreads();                                        // reads before in-place writes
    dft16<false>(v);
    {
        const int k = t & 15, j = t >> 4;
        #pragma unroll
        for (int p = 1; p < 16; ++p)
            v[IDX16(p)] = cmul(v[IDX16(p)], tw[16 * j * p]);
        #pragma unroll
        for (int p = 0; p < 16; ++p)
            lds[SWZ(k + 256 * j + 16 * p)] = v[IDX16(p)];
    }
    __syncthreads();

    // ---- fwd C (m=256, j=0, no twiddle) + pointwise H, all in registers ----
    #pragma unroll
    for (int r = 0; r < 16; ++r) v[r] = lds[SWZ(t + 256 * r)];
    __syncthreads();                                        // protect inv-A writes below
    dft16<false>(v);
    // slot q holds spectrum element at natural index t + 256*IDX16(q)
    #pragma unroll
    for (int q = 0; q < 16; ++q)
        v[q] = cmul(v[q], H[t + 256 * IDX16(q)]);

    // ---- inv A (m=1): input is IDX16-permuted in regs -> dft16_perm ----
    dft16_perm<true>(v);                                    // output X_p at slot p
    #pragma unroll
    for (int p = 1; p < 16; ++p) {
        float2 w = tw[t * p]; w.y = -w.y;
        v[p] = cmul(v[p], w);
    }
    #pragma unroll
    for (int p = 0; p < 16; ++p)
        lds[SWZ(16 * t + p)] = v[p];
    __syncthreads();

    // ---- inv B (m=16) ----
    #pragma unroll
    for (int r = 0; r < 16; ++r) v[r] = lds[SWZ(t + 256 * r)];
    __syncthreads();
    dft16<true>(v);
    {
        const int k = t & 15, j = t >> 4;
        #pragma unroll
        for (int p = 1; p < 16; ++p) {
            float2 w = tw[16 * j * p]; w.y = -w.y;
            v[IDX16(p)] = cmul(v[IDX16(p)], w);
        }
        #pragma unroll
        for (int p = 0; p < 16; ++p)
            lds[SWZ(k + 256 * j + 16 * p)] = v[IDX16(p)];
    }
    __syncthreads();

    // ---- inv C (m=256) + scale/bias epilogue straight to global ----
    #pragma unroll
    for (int r = 0; r < 16; ++r) v[r] = lds[SWZ(t + 256 * r)];
    dft16<true>(v);
    const float inv = 1.0f / (float)N;
    #pragma unroll
    for (int p = 0; p < 16; ++p) {
        float2 val = v[IDX16(p)];
        float bb = bias[t + 256 * p];
        out[base1 + t + 256 * p] = fmaf(val.x, inv, bb);
        out[base2 + t + 256 * p] = fmaf(val.y, inv, bb);
    }
}

// ---------------------------------------------------------------------------
extern "C" void kernel_launch(void* const* d_in, const int* in_sizes, int n_in,
                              void* d_out, int out_size, void* d_ws, size_t ws_size,
                              hipStream_t stream) {
    const float* x  = (const float*)d_in[0];   // (8192, 4096)
    const float* wr = (const float*)d_in[1];   // (2049,)
    const float* wi = (const float*)d_in[2];   // (2049,)
    const float* bs = (const float*)d_in[3];   // (4096,)
    float* out = (float*)d_out;                // (8192, 4096)

    float2* H  = (float2*)d_ws;                                       // 32 KB
    float2* tw = (float2*)((char*)d_ws + (size_t)N * sizeof(float2)); // 32 KB

    prep_kernel<<<dim3(N / THREADS), dim3(THREADS), 0, stream>>>(wr, wi, H, tw);
    fft_conv_kernel<<<dim3(BATCH / 2), dim3(THREADS), 0, stream>>>(x, H, tw, bs, out);
}